// Round 1
// baseline (429.085 us; speedup 1.0000x reference)
//
#include <hip/hip_runtime.h>

// Problem constants (match reference file)
#define T_TOK 10
#define NN    4096
#define NE    65536
#define DF    128
#define DPE   32
#define LSPD  4
#define BB    64

#define TN    (T_TOK + NN)            // 4106 nodes per graph after token prepend
#define EI    (T_TOK * (T_TOK - 1))   // 90 inner prompt edges
#define EC    (2 * T_TOK * NN)        // 81920 undirected cross edges
#define ETOT  (EI + NE + EC)          // 147546 edges per graph
#define BE    (BB * ETOT)             // 9,442,944 total edges

// Output region sizes (flat f32 elements, concatenated in return order)
#define SX ((long long)BB * TN * DF)   // 33,636,352  x
#define SP ((long long)BB * TN * DPE)  //  8,409,088  pe
#define SE (2LL * BE)                  // 18,885,888  edge_index
#define SW ((long long)BE)             //  9,442,944  edge_weight

// ---------------------------------------------------------------- x fill
// One thread per float4 of the output x. Rows < T come from token_list,
// the rest from g_x[b]. D=128 floats -> 32 float4 per row.
__global__ __launch_bounds__(256) void k_fill_x(
    const float4* __restrict__ gx, const float4* __restrict__ tok,
    float4* __restrict__ ox, int total)
{
    const int R4 = DF / 4;  // 32
    for (int i = blockIdx.x * blockDim.x + threadIdx.x; i < total;
         i += gridDim.x * blockDim.x) {
        int row = i >> 5;          // i / 32
        int c   = i & 31;
        int b   = row / TN;
        int lr  = row - b * TN;
        float4 v;
        if (lr < T_TOK) v = tok[lr * R4 + c];
        else            v = gx[(b * NN + (lr - T_TOK)) * R4 + c];
        ox[i] = v;
    }
}

// ---------------------------------------------------------------- pe fill
// PE=32 floats -> 8 float4 per row.
__global__ __launch_bounds__(256) void k_fill_pe(
    const float4* __restrict__ gpe, const float4* __restrict__ tokpe,
    float4* __restrict__ ope, int total)
{
    const int R4 = DPE / 4;  // 8
    for (int i = blockIdx.x * blockDim.x + threadIdx.x; i < total;
         i += gridDim.x * blockDim.x) {
        int row = i >> 3;          // i / 8
        int c   = i & 7;
        int b   = row / TN;
        int lr  = row - b * TN;
        float4 v;
        if (lr < T_TOK) v = tokpe[lr * R4 + c];
        else            v = gpe[(b * NN + (lr - T_TOK)) * R4 + c];
        ope[i] = v;
    }
}

// ---------------------------------------------------------------- edges
// One thread per (b, e). Writes src (row 0), dst (row 1) of edge_index and
// edge_weight, all as exact float32 values.
__global__ __launch_bounds__(256) void k_edges(
    const int* __restrict__ gei, const int* __restrict__ spd,
    const float* __restrict__ ewp, const float* __restrict__ swp,
    float* __restrict__ oei, float* __restrict__ oew)
{
    for (int i = blockIdx.x * blockDim.x + threadIdx.x; i < BE;
         i += gridDim.x * blockDim.x) {
        int b = i / ETOT;
        int e = i - b * ETOT;
        int base = b * TN;
        int s, d;
        float w;
        if (e < EI) {
            // complete graph on tokens minus self loops, row-major
            int ii = e / (T_TOK - 1);
            int k  = e - ii * (T_TOK - 1);
            int jj = k + (k >= ii ? 1 : 0);
            s = ii; d = jj;
            w = swp[0];
        } else if (e < EI + NE) {
            int ge = e - EI;
            s = gei[(2 * b + 0) * NE + ge] + T_TOK;
            d = gei[(2 * b + 1) * NE + ge] + T_TOK;
            w = 1.0f;
        } else {
            int c = e - EI - NE;
            int n;
            if (c < T_TOK * NN) {           // forward: token -> node
                int t = c >> 12;            // c / 4096
                n = c & (NN - 1);
                s = t; d = n + T_TOK;
            } else {                        // reversed: node -> token
                int c2 = c - T_TOK * NN;
                int t = c2 >> 12;
                n = c2 & (NN - 1);
                s = n + T_TOK; d = t;
            }
            int sv = spd[b * NN + n];
            sv = min(max(sv, 0), LSPD);
            w = ewp[sv];
        }
        s += base; d += base;
        oei[i]            = (float)s;
        oei[(long long)BE + i] = (float)d;
        oew[i] = w;
    }
}

// ---------------------------------------------------------------- root
__global__ __launch_bounds__(64) void k_root(
    const int* __restrict__ groot, float* __restrict__ oroot)
{
    int b = threadIdx.x;
    if (b < BB) oroot[b] = (float)(groot[b] + T_TOK + b * TN);
}

extern "C" void kernel_launch(void* const* d_in, const int* in_sizes, int n_in,
                              void* d_out, int out_size, void* d_ws, size_t ws_size,
                              hipStream_t stream) {
    const float* g_x       = (const float*)d_in[0];
    const float* g_pe      = (const float*)d_in[1];
    const int*   g_ei      = (const int*)d_in[2];
    const int*   g_spd     = (const int*)d_in[3];
    const int*   g_root    = (const int*)d_in[4];
    const float* token     = (const float*)d_in[5];
    const float* token_pe  = (const float*)d_in[6];
    const float* shared_w  = (const float*)d_in[7];
    const float* ew_param  = (const float*)d_in[8];

    float* out    = (float*)d_out;
    float* out_x  = out;
    float* out_pe = out + SX;
    float* out_ei = out + SX + SP;
    float* out_ew = out + SX + SP + SE;
    float* out_rt = out + SX + SP + SE + SW;

    {
        int total = (int)(SX / 4);  // 8,409,088 float4
        int blocks = (total + 255) / 256;
        k_fill_x<<<blocks, 256, 0, stream>>>(
            (const float4*)g_x, (const float4*)token, (float4*)out_x, total);
    }
    {
        int total = (int)(SP / 4);  // 2,102,272 float4
        int blocks = (total + 255) / 256;
        k_fill_pe<<<blocks, 256, 0, stream>>>(
            (const float4*)g_pe, (const float4*)token_pe, (float4*)out_pe, total);
    }
    {
        int blocks = (BE + 255) / 256;  // 36,887
        k_edges<<<blocks, 256, 0, stream>>>(
            g_ei, g_spd, ew_param, shared_w, out_ei, out_ew);
    }
    k_root<<<1, 64, 0, stream>>>(g_root, out_rt);
}